// Round 9
// baseline (552.791 us; speedup 1.0000x reference)
//
#include <hip/hip_runtime.h>

// TalkingHeadAttention: B=4, N=1024, C=768, H=12, HD=64
// Round 9: occupancy fixes on the round-8 structure (algebra unchanged).
//  - pvmix_k: grid 1024 (key QUARTERS) + __launch_bounds__(256,4)
//    => 4 waves/SIMD (was grid-limited to 2). 4 atomic contribs/element.
//  - dsum_k: __launch_bounds__(256,4) => <=128 VGPR (was 175 -> 256 quantum
//    -> 2 waves/SIMD). Grid 2048 already supplies 8 waves/SIMD of demand.
// b_l dropped (cancels in softmax); b_w folded into mixed-prob init.

#define Bsz   4
#define Nseq  1024
#define Cdim  768
#define Hn    12
#define HDim  64

typedef __attribute__((ext_vector_type(4))) float    f32x4;
typedef __attribute__((ext_vector_type(8))) _Float16 f16x8;
typedef __attribute__((ext_vector_type(4))) _Float16 f16x4;

#define MFMA_F16(A, B, C) __builtin_amdgcn_mfma_f32_16x16x32_f16(A, B, C, 0, 0, 0)

// ---------------- fp32 -> fp16 cast ----------------------------------------
__global__ __launch_bounds__(256) void cvt_f32_f16(
    const float* __restrict__ in, _Float16* __restrict__ out)
{
  const size_t i = (size_t)(blockIdx.x * 256 + threadIdx.x) * 4;
  float4 v = *(const float4*)(in + i);
  f16x4 o;
  o[0] = (_Float16)v.x; o[1] = (_Float16)v.y;
  o[2] = (_Float16)v.z; o[3] = (_Float16)v.w;
  *(f16x4*)(out + i) = o;
}

// ------------- transpose + cast: in[R][C] fp32 -> out[C][R] fp16 -----------
__global__ __launch_bounds__(256) void transpose_cvt(
    const float* __restrict__ in, _Float16* __restrict__ out, int R, int C)
{
  __shared__ float T[64][65];
  const int c0 = blockIdx.x * 64, r0 = blockIdx.y * 64;
  const int lr = threadIdx.x >> 4, lc = (threadIdx.x & 15) * 4;
#pragma unroll
  for (int i = 0; i < 4; ++i) {
    float4 v = *(const float4*)(in + (size_t)(r0 + lr + i*16) * C + c0 + lc);
    T[lr+i*16][lc+0] = v.x; T[lr+i*16][lc+1] = v.y;
    T[lr+i*16][lc+2] = v.z; T[lr+i*16][lc+3] = v.w;
  }
  __syncthreads();
#pragma unroll
  for (int i = 0; i < 4; ++i) {
    const int orow = lr + i*16;
    f16x4 o;
#pragma unroll
    for (int j = 0; j < 4; ++j) o[j] = (_Float16)T[lc+j][orow];
    *(f16x4*)(out + (size_t)(c0 + orow) * R + r0 + lc) = o;
  }
}

// ---------------- fp16 MFMA GEMM, BT form ----------------------------------
__global__ __launch_bounds__(256, 2) void gemm_f16(
    const _Float16* __restrict__ A, const _Float16* __restrict__ Bt,
    const float* __restrict__ bias, _Float16* __restrict__ C16,
    float* __restrict__ C32, int M, int N, int K)
{
  __shared__ _Float16 sA[2][4][512];
  __shared__ _Float16 sB[2][4][512];
  const int tid = threadIdx.x;
  const int w = tid >> 6, lane = tid & 63;
  const int m0 = blockIdx.y * 128, n0 = blockIdx.x * 128;
  const int frow = lane & 15, fk8 = lane >> 4;

  f32x4 acc[4][4];
#pragma unroll
  for (int i = 0; i < 4; ++i)
#pragma unroll
    for (int j = 0; j < 4; ++j) acc[i][j] = (f32x4)0.f;

  const _Float16* gsrc = (w < 2)
      ? A  + (size_t)(m0 + w*64 + frow) * K + fk8 * 8
      : Bt + (size_t)(n0 + (w - 2)*64 + frow) * K + fk8 * 8;

  for (int kt = 0; kt < K; kt += 32) {
    f16x8 st[4];
#pragma unroll
    for (int j = 0; j < 4; ++j)
      st[j] = *(const f16x8*)(gsrc + kt + (size_t)j * 16 * K);
    __syncthreads();
    if (w < 2) {
#pragma unroll
      for (int j = 0; j < 4; ++j) *(f16x8*)&sA[w][j][lane*8] = st[j];
    } else {
#pragma unroll
      for (int j = 0; j < 4; ++j) *(f16x8*)&sB[w-2][j][lane*8] = st[j];
    }
    __syncthreads();
    f16x8 af[4], bf[4];
#pragma unroll
    for (int mi = 0; mi < 4; ++mi) af[mi] = *(const f16x8*)&sA[w & 1][mi][lane*8];
#pragma unroll
    for (int ni = 0; ni < 4; ++ni) bf[ni] = *(const f16x8*)&sB[w >> 1][ni][lane*8];
#pragma unroll
    for (int mi = 0; mi < 4; ++mi)
#pragma unroll
      for (int ni = 0; ni < 4; ++ni)
        acc[mi][ni] = MFMA_F16(af[mi], bf[ni], acc[mi][ni]);
  }

  const int m0w = m0 + (w & 1) * 64, n0w = n0 + (w >> 1) * 64;
#pragma unroll
  for (int mi = 0; mi < 4; ++mi)
#pragma unroll
    for (int ni = 0; ni < 4; ++ni) {
      const int n = n0w + ni*16 + (lane & 15);
#pragma unroll
      for (int r = 0; r < 4; ++r) {
        const int m = m0w + mi*16 + (lane >> 4)*4 + r;
        if (C16) C16[(size_t)m * N + n] = (_Float16)acc[mi][ni][r];
        else     C32[(size_t)m * N + n] = acc[mi][ni][r] + bias[n];
      }
    }
}

// ---------------- prep: V block of qkv16 -> per-head V^T fp16 --------------
__global__ __launch_bounds__(256) void prep_v(
    const _Float16* __restrict__ qkv16, _Float16* __restrict__ Vt)
{
  __shared__ float vt[64][65];
  const int id = blockIdx.x;
  const int nt = id & 15;
  const int h  = (id >> 4) % Hn;
  const int b  = id / (16 * Hn);
  const int n0 = nt * 64;
  const int tid = threadIdx.x;
  const int row = tid >> 2;
  const int c0  = (tid & 3) * 16;

  const _Float16* src = qkv16 + (size_t)(b*Nseq + n0 + row) * (3*Cdim) + 2*Cdim + h*HDim + c0;
  f16x8 v0 = *(const f16x8*)src;
  f16x8 v1 = *(const f16x8*)(src + 8);
#pragma unroll
  for (int j = 0; j < 8; ++j) {
    vt[c0+j][row]   = (float)v0[j];
    vt[c0+8+j][row] = (float)v1[j];
  }
  __syncthreads();
  f16x8 o0, o1;
#pragma unroll
  for (int j = 0; j < 8; ++j) {
    o0[j] = (_Float16)vt[row][c0+j];
    o1[j] = (_Float16)vt[row][c0+8+j];
  }
  _Float16* dst = Vt + (size_t)((b*Hn + h)*HDim + row) * Nseq + n0 + c0;
  *(f16x8*)dst = o0;
  *(f16x8*)(dst + 8) = o1;
}

// ---------------- denominator kernel ---------------------------------------
// grid = b(4) x qtile(64) x chunk(8) = 2048; 256 thr, 4 waves. Wave w owns
// keys ch*128 + kg*64 + w*16 + col (kg=0,1), all 12 heads, S in registers.
// Cross-wave reduction via dred LDS, then one write per (row, chunk).
__global__ __launch_bounds__(256, 4) void dsum_k(
    const _Float16* __restrict__ qkv16, const float* __restrict__ w_l,
    float* __restrict__ dpart)
{
  __shared__ __attribute__((aligned(16))) float wl_s[144];
  __shared__ float dred[4][16][12];
  const int tid = threadIdx.x;
  const int w = tid >> 6, lane = tid & 63;
  const int col = lane & 15, grp = lane >> 4;
  const int ch = blockIdx.x & 7;
  const int qt = (blockIdx.x >> 3) & 63;
  const int b  = blockIdx.x >> 9;
  const int q0 = qt << 4;

  if (tid < 144) wl_s[tid] = w_l[tid] * 0.125f;

  f16x8 qf[12][2];
  {
    const _Float16* qrow = qkv16 + (size_t)(b*Nseq + q0 + col) * (3*Cdim) + grp*8;
#pragma unroll
    for (int h = 0; h < 12; ++h) {
      qf[h][0] = *(const f16x8*)(qrow + h*HDim);
      qf[h][1] = *(const f16x8*)(qrow + h*HDim + 32);
    }
  }
  __syncthreads();

  float dacc[4][12];
#pragma unroll
  for (int r = 0; r < 4; ++r)
#pragma unroll
    for (int g = 0; g < 12; ++g) dacc[r][g] = 0.f;

#pragma unroll
  for (int kg = 0; kg < 2; ++kg) {
    const int key = ch*128 + kg*64 + w*16 + col;
    const _Float16* krow = qkv16 + (size_t)(b*Nseq + key) * (3*Cdim) + Cdim + grp*8;
    f32x4 S[12];
#pragma unroll
    for (int h = 0; h < 12; ++h) {
      f16x8 b0 = *(const f16x8*)(krow + h*HDim);
      f16x8 b1 = *(const f16x8*)(krow + h*HDim + 32);
      f32x4 s = (f32x4)0.f;
      s = MFMA_F16(qf[h][0], b0, s);
      S[h] = MFMA_F16(qf[h][1], b1, s);
    }
#pragma unroll
    for (int r = 0; r < 4; ++r) {
      float L[12];
#pragma unroll
      for (int g = 0; g < 12; ++g) L[g] = 0.f;
#pragma unroll
      for (int h = 0; h < 12; ++h) {
        const float s = S[h][r];
        const f32x4 w0 = *(const f32x4*)&wl_s[h*12];
        const f32x4 w1 = *(const f32x4*)&wl_s[h*12+4];
        const f32x4 w2 = *(const f32x4*)&wl_s[h*12+8];
#pragma unroll
        for (int j = 0; j < 4; ++j) {
          L[j]   = fmaf(s, w0[j], L[j]);
          L[4+j] = fmaf(s, w1[j], L[4+j]);
          L[8+j] = fmaf(s, w2[j], L[8+j]);
        }
      }
#pragma unroll
      for (int g = 0; g < 12; ++g) dacc[r][g] += __expf(L[g] - 6.0f);
    }
  }
  // reduce over this wave's 16 key-lanes (xor low 4 bits keeps grp)
#pragma unroll
  for (int r = 0; r < 4; ++r)
#pragma unroll
    for (int g = 0; g < 12; ++g) {
      float v = dacc[r][g];
      v += __shfl_xor(v, 1, 64);
      v += __shfl_xor(v, 2, 64);
      v += __shfl_xor(v, 4, 64);
      v += __shfl_xor(v, 8, 64);
      dacc[r][g] = v;
    }
  if (col == 0) {
#pragma unroll
    for (int r = 0; r < 4; ++r)
#pragma unroll
      for (int g = 0; g < 12; ++g) dred[w][grp*4+r][g] = dacc[r][g];
  }
  __syncthreads();
  // cross-wave sum, one write per (q,g) row for this chunk
  if (tid < 192) {
    const int q = tid / 12, g = tid % 12;
    const float s = dred[0][q][g] + dred[1][q][g] + dred[2][q][g] + dred[3][q][g];
    dpart[((size_t)((b*Hn + g)*Nseq) + q0 + q) * 8 + ch] = s;
  }
}

// ---------------- 1/d reduction --------------------------------------------
__global__ __launch_bounds__(256) void dinv_k(
    const float* __restrict__ dpart, float* __restrict__ dinv)
{
  const int i = blockIdx.x * 256 + threadIdx.x;   // 49152 rows
  const float* p = dpart + (size_t)i * 8;
  f32x4 a = *(const f32x4*)p;
  f32x4 c = *(const f32x4*)(p + 4);
  dinv[i] = 1.0f / (a[0]+a[1]+a[2]+a[3]+c[0]+c[1]+c[2]+c[3]);
}

// ---------------- pass B: normalize + w_w mix + PV -------------------------
// grid = b(4) x qtile(64) x keyquarter(4) = 1024 blocks; 256 thr, 4 waves.
// Each block handles 4 chunks of 64 keys; 4 atomic contribs per x element.
__global__ __launch_bounds__(256, 4) void pvmix_k(
    const _Float16* __restrict__ qkv16, const _Float16* __restrict__ Vt,
    const float* __restrict__ dinv,
    const float* __restrict__ w_l, const float* __restrict__ w_w,
    const float* __restrict__ b_w, float* __restrict__ x32)
{
  __shared__ _Float16 P_s[12][16][72];
  __shared__ float dinv_s[16][12];
  __shared__ __attribute__((aligned(16))) float wl_s[144];
  __shared__ __attribute__((aligned(16))) float ww_s[144];
  __shared__ float bw_s[12];

  const int tid = threadIdx.x;
  const int w = tid >> 6, lane = tid & 63;
  const int col = lane & 15, grp = lane >> 4;
  const int kq = blockIdx.x & 3;
  const int qt = (blockIdx.x >> 2) & 63;
  const int b  = blockIdx.x >> 8;
  const int q0 = qt << 4;

  if (tid < 144) { wl_s[tid] = w_l[tid] * 0.125f; ww_s[tid] = w_w[tid]; }
  if (tid < 12)  bw_s[tid] = b_w[tid];
  if (tid < 192) {
    const int q = tid / 12, g = tid % 12;
    dinv_s[q][g] = dinv[(size_t)((b*Hn + g)*Nseq) + q0 + q];
  }

  f16x8 qf[12][2];
  {
    const _Float16* qrow = qkv16 + (size_t)(b*Nseq + q0 + col) * (3*Cdim) + grp*8;
#pragma unroll
    for (int h = 0; h < 12; ++h) {
      qf[h][0] = *(const f16x8*)(qrow + h*HDim);
      qf[h][1] = *(const f16x8*)(qrow + h*HDim + 32);
    }
  }
  __syncthreads();

  f32x4 Y[12];
#pragma unroll
  for (int g2 = 0; g2 < 12; ++g2) Y[g2] = (f32x4)0.f;

  for (int c = kq*4; c < kq*4 + 4; ++c) {
    const int k0 = c * 64;
    const _Float16* krow = qkv16 + (size_t)(b*Nseq + k0 + w*16 + col) * (3*Cdim)
                           + Cdim + grp*8;
    f32x4 S[12];
#pragma unroll
    for (int h = 0; h < 12; ++h) {
      f16x8 b0 = *(const f16x8*)(krow + h*HDim);
      f16x8 b1 = *(const f16x8*)(krow + h*HDim + 32);
      f32x4 s = (f32x4)0.f;
      s = MFMA_F16(qf[h][0], b0, s);
      S[h] = MFMA_F16(qf[h][1], b1, s);
    }
    __syncthreads();   // previous chunk's PV reads of P_s complete
#pragma unroll
    for (int r = 0; r < 4; ++r) {
      const int q = grp*4 + r;
      float L[12];
#pragma unroll
      for (int g = 0; g < 12; ++g) L[g] = 0.f;
#pragma unroll
      for (int h = 0; h < 12; ++h) {
        const float s = S[h][r];
        const f32x4 w0 = *(const f32x4*)&wl_s[h*12];
        const f32x4 w1 = *(const f32x4*)&wl_s[h*12+4];
        const f32x4 w2 = *(const f32x4*)&wl_s[h*12+8];
#pragma unroll
        for (int j = 0; j < 4; ++j) {
          L[j]   = fmaf(s, w0[j], L[j]);
          L[4+j] = fmaf(s, w1[j], L[4+j]);
          L[8+j] = fmaf(s, w2[j], L[8+j]);
        }
      }
      float att2[12];
#pragma unroll
      for (int g2 = 0; g2 < 12; ++g2) att2[g2] = bw_s[g2];
#pragma unroll
      for (int g = 0; g < 12; ++g) {
        const float pr = __expf(L[g] - 6.0f) * dinv_s[q][g];
        const f32x4 w0 = *(const f32x4*)&ww_s[g*12];
        const f32x4 w1 = *(const f32x4*)&ww_s[g*12+4];
        const f32x4 w2 = *(const f32x4*)&ww_s[g*12+8];
#pragma unroll
        for (int j = 0; j < 4; ++j) {
          att2[j]   = fmaf(pr, w0[j], att2[j]);
          att2[4+j] = fmaf(pr, w1[j], att2[4+j]);
          att2[8+j] = fmaf(pr, w2[j], att2[8+j]);
        }
      }
#pragma unroll
      for (int g2 = 0; g2 < 12; ++g2)
        P_s[g2][q][w*16 + col] = (_Float16)att2[g2];
    }
    __syncthreads();   // P_s complete
#pragma unroll
    for (int g2 = 0; g2 < 12; ++g2) {
      f16x8 a0 = *(const f16x8*)&P_s[g2][col][grp*8];
      f16x8 a1 = *(const f16x8*)&P_s[g2][col][32 + grp*8];
      const _Float16* vb = Vt + (size_t)((b*Hn + g2)*HDim + w*16 + col) * Nseq
                           + k0 + grp*8;
      f16x8 v0 = *(const f16x8*)vb;
      f16x8 v1 = *(const f16x8*)(vb + 32);
      Y[g2] = MFMA_F16(a0, v0, Y[g2]);
      Y[g2] = MFMA_F16(a1, v1, Y[g2]);
    }
  }

  // merge the four key-quarters via fp32 atomics
#pragma unroll
  for (int g2 = 0; g2 < 12; ++g2)
#pragma unroll
    for (int r = 0; r < 4; ++r)
      atomicAdd(&x32[(size_t)(b*Nseq + q0 + grp*4 + r) * Cdim + g2*HDim + w*16 + col],
                Y[g2][r]);
}

extern "C" void kernel_launch(void* const* d_in, const int* in_sizes, int n_in,
                              void* d_out, int out_size, void* d_ws, size_t ws_size,
                              hipStream_t stream) {
  (void)in_sizes; (void)n_in; (void)out_size; (void)ws_size;
  const float* inputs = (const float*)d_in[0];
  const float* w_qkv  = (const float*)d_in[1];
  const float* w_l    = (const float*)d_in[2];
  // d_in[3] = b_l: cancels in softmax — unused.
  const float* w_w    = (const float*)d_in[4];
  const float* b_w    = (const float*)d_in[5];
  const float* w_proj = (const float*)d_in[6];
  const float* b_proj = (const float*)d_in[7];
  float* out = (float*)d_out;

  const int M = Bsz * Nseq;  // 4096
  char* ws = (char*)d_ws;
  _Float16* A16   = (_Float16*)ws;                   // 4096x768
  _Float16* BtQKV = A16   + (size_t)M * Cdim;        // 2304x768
  _Float16* BtPrj = BtQKV + (size_t)(3*Cdim) * Cdim; // 768x768
  _Float16* qkv16 = BtPrj + (size_t)Cdim * Cdim;     // 4096x2304
  _Float16* Vt    = qkv16 + (size_t)M * 3 * Cdim;    // (B*H*64)x1024
  _Float16* x16   = Vt    + (size_t)M * Cdim;        // 4096x768
  float*    dpart = (float*)(x16 + (size_t)M * Cdim);        // 49152x8
  float*    dinv  = dpart + (size_t)Bsz*Hn*Nseq*8;           // 49152
  float*    x32   = dinv  + (size_t)Bsz*Hn*Nseq;             // 4096x768

  cvt_f32_f16<<<dim3((M * Cdim) / 1024), 256, 0, stream>>>(inputs, A16);
  transpose_cvt<<<dim3((3*Cdim)/64, Cdim/64), 256, 0, stream>>>(w_qkv, BtQKV, Cdim, 3*Cdim);
  transpose_cvt<<<dim3(Cdim/64, Cdim/64), 256, 0, stream>>>(w_proj, BtPrj, Cdim, Cdim);

  gemm_f16<<<dim3((3*Cdim)/128, M/128), 256, 0, stream>>>(
      A16, BtQKV, nullptr, qkv16, nullptr, M, 3*Cdim, Cdim);

  prep_v<<<dim3(Bsz*Hn*16), 256, 0, stream>>>(qkv16, Vt);

  dsum_k<<<dim3(Bsz*64*8), 256, 0, stream>>>(qkv16, w_l, dpart);
  dinv_k<<<dim3(Bsz*Hn*Nseq/256), 256, 0, stream>>>(dpart, dinv);

  hipMemsetAsync(x32, 0, (size_t)M*Cdim*sizeof(float), stream);
  pvmix_k<<<dim3(Bsz*64*4), 256, 0, stream>>>(
      qkv16, Vt, dinv, w_l, w_w, b_w, x32);

  cvt_f32_f16<<<dim3((M * Cdim) / 1024), 256, 0, stream>>>(x32, x16);

  gemm_f16<<<dim3(Cdim/128, M/128), 256, 0, stream>>>(
      x16, BtPrj, b_proj, nullptr, out, M, Cdim, Cdim);
}

// Round 10
// 420.366 us; speedup vs baseline: 1.3150x; 1.3150x over previous
//
#include <hip/hip_runtime.h>

// TalkingHeadAttention: B=4, N=1024, C=768, H=12, HD=64
// Round 10: round-8 structure (verified 405us). ONE change: pvmix_k grid
// 512 -> 1024 (key QUARTERS) keeping __launch_bounds__(256,2) — round 9
// proved (256,4) forces a catastrophic spill (VGPR 64, 343MB FETCH); the
// round-8 config at 128 VGPR allows 4 waves/SIMD in HW, it was only
// grid-starved. dsum_k reverted to (256,2) (round-8 known-good).
// b_l dropped (cancels in softmax); b_w folded into mixed-prob init.

#define Bsz   4
#define Nseq  1024
#define Cdim  768
#define Hn    12
#define HDim  64

typedef __attribute__((ext_vector_type(4))) float    f32x4;
typedef __attribute__((ext_vector_type(8))) _Float16 f16x8;
typedef __attribute__((ext_vector_type(4))) _Float16 f16x4;

#define MFMA_F16(A, B, C) __builtin_amdgcn_mfma_f32_16x16x32_f16(A, B, C, 0, 0, 0)

// ---------------- fp32 -> fp16 cast ----------------------------------------
__global__ __launch_bounds__(256) void cvt_f32_f16(
    const float* __restrict__ in, _Float16* __restrict__ out)
{
  const size_t i = (size_t)(blockIdx.x * 256 + threadIdx.x) * 4;
  float4 v = *(const float4*)(in + i);
  f16x4 o;
  o[0] = (_Float16)v.x; o[1] = (_Float16)v.y;
  o[2] = (_Float16)v.z; o[3] = (_Float16)v.w;
  *(f16x4*)(out + i) = o;
}

// ------------- transpose + cast: in[R][C] fp32 -> out[C][R] fp16 -----------
__global__ __launch_bounds__(256) void transpose_cvt(
    const float* __restrict__ in, _Float16* __restrict__ out, int R, int C)
{
  __shared__ float T[64][65];
  const int c0 = blockIdx.x * 64, r0 = blockIdx.y * 64;
  const int lr = threadIdx.x >> 4, lc = (threadIdx.x & 15) * 4;
#pragma unroll
  for (int i = 0; i < 4; ++i) {
    float4 v = *(const float4*)(in + (size_t)(r0 + lr + i*16) * C + c0 + lc);
    T[lr+i*16][lc+0] = v.x; T[lr+i*16][lc+1] = v.y;
    T[lr+i*16][lc+2] = v.z; T[lr+i*16][lc+3] = v.w;
  }
  __syncthreads();
#pragma unroll
  for (int i = 0; i < 4; ++i) {
    const int orow = lr + i*16;
    f16x4 o;
#pragma unroll
    for (int j = 0; j < 4; ++j) o[j] = (_Float16)T[lc+j][orow];
    *(f16x4*)(out + (size_t)(c0 + orow) * R + r0 + lc) = o;
  }
}

// ---------------- fp16 MFMA GEMM, BT form ----------------------------------
__global__ __launch_bounds__(256, 2) void gemm_f16(
    const _Float16* __restrict__ A, const _Float16* __restrict__ Bt,
    const float* __restrict__ bias, _Float16* __restrict__ C16,
    float* __restrict__ C32, int M, int N, int K)
{
  __shared__ _Float16 sA[2][4][512];
  __shared__ _Float16 sB[2][4][512];
  const int tid = threadIdx.x;
  const int w = tid >> 6, lane = tid & 63;
  const int m0 = blockIdx.y * 128, n0 = blockIdx.x * 128;
  const int frow = lane & 15, fk8 = lane >> 4;

  f32x4 acc[4][4];
#pragma unroll
  for (int i = 0; i < 4; ++i)
#pragma unroll
    for (int j = 0; j < 4; ++j) acc[i][j] = (f32x4)0.f;

  const _Float16* gsrc = (w < 2)
      ? A  + (size_t)(m0 + w*64 + frow) * K + fk8 * 8
      : Bt + (size_t)(n0 + (w - 2)*64 + frow) * K + fk8 * 8;

  for (int kt = 0; kt < K; kt += 32) {
    f16x8 st[4];
#pragma unroll
    for (int j = 0; j < 4; ++j)
      st[j] = *(const f16x8*)(gsrc + kt + (size_t)j * 16 * K);
    __syncthreads();
    if (w < 2) {
#pragma unroll
      for (int j = 0; j < 4; ++j) *(f16x8*)&sA[w][j][lane*8] = st[j];
    } else {
#pragma unroll
      for (int j = 0; j < 4; ++j) *(f16x8*)&sB[w-2][j][lane*8] = st[j];
    }
    __syncthreads();
    f16x8 af[4], bf[4];
#pragma unroll
    for (int mi = 0; mi < 4; ++mi) af[mi] = *(const f16x8*)&sA[w & 1][mi][lane*8];
#pragma unroll
    for (int ni = 0; ni < 4; ++ni) bf[ni] = *(const f16x8*)&sB[w >> 1][ni][lane*8];
#pragma unroll
    for (int mi = 0; mi < 4; ++mi)
#pragma unroll
      for (int ni = 0; ni < 4; ++ni)
        acc[mi][ni] = MFMA_F16(af[mi], bf[ni], acc[mi][ni]);
  }

  const int m0w = m0 + (w & 1) * 64, n0w = n0 + (w >> 1) * 64;
#pragma unroll
  for (int mi = 0; mi < 4; ++mi)
#pragma unroll
    for (int ni = 0; ni < 4; ++ni) {
      const int n = n0w + ni*16 + (lane & 15);
#pragma unroll
      for (int r = 0; r < 4; ++r) {
        const int m = m0w + mi*16 + (lane >> 4)*4 + r;
        if (C16) C16[(size_t)m * N + n] = (_Float16)acc[mi][ni][r];
        else     C32[(size_t)m * N + n] = acc[mi][ni][r] + bias[n];
      }
    }
}

// ---------------- prep: V block of qkv16 -> per-head V^T fp16 --------------
__global__ __launch_bounds__(256) void prep_v(
    const _Float16* __restrict__ qkv16, _Float16* __restrict__ Vt)
{
  __shared__ float vt[64][65];
  const int id = blockIdx.x;
  const int nt = id & 15;
  const int h  = (id >> 4) % Hn;
  const int b  = id / (16 * Hn);
  const int n0 = nt * 64;
  const int tid = threadIdx.x;
  const int row = tid >> 2;
  const int c0  = (tid & 3) * 16;

  const _Float16* src = qkv16 + (size_t)(b*Nseq + n0 + row) * (3*Cdim) + 2*Cdim + h*HDim + c0;
  f16x8 v0 = *(const f16x8*)src;
  f16x8 v1 = *(const f16x8*)(src + 8);
#pragma unroll
  for (int j = 0; j < 8; ++j) {
    vt[c0+j][row]   = (float)v0[j];
    vt[c0+8+j][row] = (float)v1[j];
  }
  __syncthreads();
  f16x8 o0, o1;
#pragma unroll
  for (int j = 0; j < 8; ++j) {
    o0[j] = (_Float16)vt[row][c0+j];
    o1[j] = (_Float16)vt[row][c0+8+j];
  }
  _Float16* dst = Vt + (size_t)((b*Hn + h)*HDim + row) * Nseq + n0 + c0;
  *(f16x8*)dst = o0;
  *(f16x8*)(dst + 8) = o1;
}

// ---------------- denominator kernel ---------------------------------------
// grid = b(4) x qtile(64) x chunk(8) = 2048; 256 thr, 4 waves. Wave w owns
// keys ch*128 + kg*64 + w*16 + col (kg=0,1), all 12 heads, S in registers.
// Cross-wave reduction via dred LDS, then one write per (row, chunk).
__global__ __launch_bounds__(256, 2) void dsum_k(
    const _Float16* __restrict__ qkv16, const float* __restrict__ w_l,
    float* __restrict__ dpart)
{
  __shared__ __attribute__((aligned(16))) float wl_s[144];
  __shared__ float dred[4][16][12];
  const int tid = threadIdx.x;
  const int w = tid >> 6, lane = tid & 63;
  const int col = lane & 15, grp = lane >> 4;
  const int ch = blockIdx.x & 7;
  const int qt = (blockIdx.x >> 3) & 63;
  const int b  = blockIdx.x >> 9;
  const int q0 = qt << 4;

  if (tid < 144) wl_s[tid] = w_l[tid] * 0.125f;

  f16x8 qf[12][2];
  {
    const _Float16* qrow = qkv16 + (size_t)(b*Nseq + q0 + col) * (3*Cdim) + grp*8;
#pragma unroll
    for (int h = 0; h < 12; ++h) {
      qf[h][0] = *(const f16x8*)(qrow + h*HDim);
      qf[h][1] = *(const f16x8*)(qrow + h*HDim + 32);
    }
  }
  __syncthreads();

  float dacc[4][12];
#pragma unroll
  for (int r = 0; r < 4; ++r)
#pragma unroll
    for (int g = 0; g < 12; ++g) dacc[r][g] = 0.f;

#pragma unroll
  for (int kg = 0; kg < 2; ++kg) {
    const int key = ch*128 + kg*64 + w*16 + col;
    const _Float16* krow = qkv16 + (size_t)(b*Nseq + key) * (3*Cdim) + Cdim + grp*8;
    f32x4 S[12];
#pragma unroll
    for (int h = 0; h < 12; ++h) {
      f16x8 b0 = *(const f16x8*)(krow + h*HDim);
      f16x8 b1 = *(const f16x8*)(krow + h*HDim + 32);
      f32x4 s = (f32x4)0.f;
      s = MFMA_F16(qf[h][0], b0, s);
      S[h] = MFMA_F16(qf[h][1], b1, s);
    }
#pragma unroll
    for (int r = 0; r < 4; ++r) {
      float L[12];
#pragma unroll
      for (int g = 0; g < 12; ++g) L[g] = 0.f;
#pragma unroll
      for (int h = 0; h < 12; ++h) {
        const float s = S[h][r];
        const f32x4 w0 = *(const f32x4*)&wl_s[h*12];
        const f32x4 w1 = *(const f32x4*)&wl_s[h*12+4];
        const f32x4 w2 = *(const f32x4*)&wl_s[h*12+8];
#pragma unroll
        for (int j = 0; j < 4; ++j) {
          L[j]   = fmaf(s, w0[j], L[j]);
          L[4+j] = fmaf(s, w1[j], L[4+j]);
          L[8+j] = fmaf(s, w2[j], L[8+j]);
        }
      }
#pragma unroll
      for (int g = 0; g < 12; ++g) dacc[r][g] += __expf(L[g] - 6.0f);
    }
  }
  // reduce over this wave's 16 key-lanes (xor low 4 bits keeps grp)
#pragma unroll
  for (int r = 0; r < 4; ++r)
#pragma unroll
    for (int g = 0; g < 12; ++g) {
      float v = dacc[r][g];
      v += __shfl_xor(v, 1, 64);
      v += __shfl_xor(v, 2, 64);
      v += __shfl_xor(v, 4, 64);
      v += __shfl_xor(v, 8, 64);
      dacc[r][g] = v;
    }
  if (col == 0) {
#pragma unroll
    for (int r = 0; r < 4; ++r)
#pragma unroll
      for (int g = 0; g < 12; ++g) dred[w][grp*4+r][g] = dacc[r][g];
  }
  __syncthreads();
  // cross-wave sum, one write per (q,g) row for this chunk
  if (tid < 192) {
    const int q = tid / 12, g = tid % 12;
    const float s = dred[0][q][g] + dred[1][q][g] + dred[2][q][g] + dred[3][q][g];
    dpart[((size_t)((b*Hn + g)*Nseq) + q0 + q) * 8 + ch] = s;
  }
}

// ---------------- 1/d reduction --------------------------------------------
__global__ __launch_bounds__(256) void dinv_k(
    const float* __restrict__ dpart, float* __restrict__ dinv)
{
  const int i = blockIdx.x * 256 + threadIdx.x;   // 49152 rows
  const float* p = dpart + (size_t)i * 8;
  f32x4 a = *(const f32x4*)p;
  f32x4 c = *(const f32x4*)(p + 4);
  dinv[i] = 1.0f / (a[0]+a[1]+a[2]+a[3]+c[0]+c[1]+c[2]+c[3]);
}

// ---------------- pass B: normalize + w_w mix + PV -------------------------
// grid = b(4) x qtile(64) x keyquarter(4) = 1024 blocks; 256 thr, 4 waves.
// __launch_bounds__(256,2): round-8-proven no-spill config (VGPR 128; HW
// then allows 4 waves/SIMD — the 1024-block grid now supplies them).
__global__ __launch_bounds__(256, 2) void pvmix_k(
    const _Float16* __restrict__ qkv16, const _Float16* __restrict__ Vt,
    const float* __restrict__ dinv,
    const float* __restrict__ w_l, const float* __restrict__ w_w,
    const float* __restrict__ b_w, float* __restrict__ x32)
{
  __shared__ _Float16 P_s[12][16][72];
  __shared__ float dinv_s[16][12];
  __shared__ __attribute__((aligned(16))) float wl_s[144];
  __shared__ __attribute__((aligned(16))) float ww_s[144];
  __shared__ float bw_s[12];

  const int tid = threadIdx.x;
  const int w = tid >> 6, lane = tid & 63;
  const int col = lane & 15, grp = lane >> 4;
  const int kq = blockIdx.x & 3;
  const int qt = (blockIdx.x >> 2) & 63;
  const int b  = blockIdx.x >> 8;
  const int q0 = qt << 4;

  if (tid < 144) { wl_s[tid] = w_l[tid] * 0.125f; ww_s[tid] = w_w[tid]; }
  if (tid < 12)  bw_s[tid] = b_w[tid];
  if (tid < 192) {
    const int q = tid / 12, g = tid % 12;
    dinv_s[q][g] = dinv[(size_t)((b*Hn + g)*Nseq) + q0 + q];
  }

  f16x8 qf[12][2];
  {
    const _Float16* qrow = qkv16 + (size_t)(b*Nseq + q0 + col) * (3*Cdim) + grp*8;
#pragma unroll
    for (int h = 0; h < 12; ++h) {
      qf[h][0] = *(const f16x8*)(qrow + h*HDim);
      qf[h][1] = *(const f16x8*)(qrow + h*HDim + 32);
    }
  }
  __syncthreads();

  f32x4 Y[12];
#pragma unroll
  for (int g2 = 0; g2 < 12; ++g2) Y[g2] = (f32x4)0.f;

  for (int c = kq*4; c < kq*4 + 4; ++c) {
    const int k0 = c * 64;
    const _Float16* krow = qkv16 + (size_t)(b*Nseq + k0 + w*16 + col) * (3*Cdim)
                           + Cdim + grp*8;
    f32x4 S[12];
#pragma unroll
    for (int h = 0; h < 12; ++h) {
      f16x8 b0 = *(const f16x8*)(krow + h*HDim);
      f16x8 b1 = *(const f16x8*)(krow + h*HDim + 32);
      f32x4 s = (f32x4)0.f;
      s = MFMA_F16(qf[h][0], b0, s);
      S[h] = MFMA_F16(qf[h][1], b1, s);
    }
    __syncthreads();   // previous chunk's PV reads of P_s complete
#pragma unroll
    for (int r = 0; r < 4; ++r) {
      const int q = grp*4 + r;
      float L[12];
#pragma unroll
      for (int g = 0; g < 12; ++g) L[g] = 0.f;
#pragma unroll
      for (int h = 0; h < 12; ++h) {
        const float s = S[h][r];
        const f32x4 w0 = *(const f32x4*)&wl_s[h*12];
        const f32x4 w1 = *(const f32x4*)&wl_s[h*12+4];
        const f32x4 w2 = *(const f32x4*)&wl_s[h*12+8];
#pragma unroll
        for (int j = 0; j < 4; ++j) {
          L[j]   = fmaf(s, w0[j], L[j]);
          L[4+j] = fmaf(s, w1[j], L[4+j]);
          L[8+j] = fmaf(s, w2[j], L[8+j]);
        }
      }
      float att2[12];
#pragma unroll
      for (int g2 = 0; g2 < 12; ++g2) att2[g2] = bw_s[g2];
#pragma unroll
      for (int g = 0; g < 12; ++g) {
        const float pr = __expf(L[g] - 6.0f) * dinv_s[q][g];
        const f32x4 w0 = *(const f32x4*)&ww_s[g*12];
        const f32x4 w1 = *(const f32x4*)&ww_s[g*12+4];
        const f32x4 w2 = *(const f32x4*)&ww_s[g*12+8];
#pragma unroll
        for (int j = 0; j < 4; ++j) {
          att2[j]   = fmaf(pr, w0[j], att2[j]);
          att2[4+j] = fmaf(pr, w1[j], att2[4+j]);
          att2[8+j] = fmaf(pr, w2[j], att2[8+j]);
        }
      }
#pragma unroll
      for (int g2 = 0; g2 < 12; ++g2)
        P_s[g2][q][w*16 + col] = (_Float16)att2[g2];
    }
    __syncthreads();   // P_s complete
#pragma unroll
    for (int g2 = 0; g2 < 12; ++g2) {
      f16x8 a0 = *(const f16x8*)&P_s[g2][col][grp*8];
      f16x8 a1 = *(const f16x8*)&P_s[g2][col][32 + grp*8];
      const _Float16* vb = Vt + (size_t)((b*Hn + g2)*HDim + w*16 + col) * Nseq
                           + k0 + grp*8;
      f16x8 v0 = *(const f16x8*)vb;
      f16x8 v1 = *(const f16x8*)(vb + 32);
      Y[g2] = MFMA_F16(a0, v0, Y[g2]);
      Y[g2] = MFMA_F16(a1, v1, Y[g2]);
    }
  }

  // merge the four key-quarters via fp32 atomics
#pragma unroll
  for (int g2 = 0; g2 < 12; ++g2)
#pragma unroll
    for (int r = 0; r < 4; ++r)
      atomicAdd(&x32[(size_t)(b*Nseq + q0 + grp*4 + r) * Cdim + g2*HDim + w*16 + col],
                Y[g2][r]);
}

extern "C" void kernel_launch(void* const* d_in, const int* in_sizes, int n_in,
                              void* d_out, int out_size, void* d_ws, size_t ws_size,
                              hipStream_t stream) {
  (void)in_sizes; (void)n_in; (void)out_size; (void)ws_size;
  const float* inputs = (const float*)d_in[0];
  const float* w_qkv  = (const float*)d_in[1];
  const float* w_l    = (const float*)d_in[2];
  // d_in[3] = b_l: cancels in softmax — unused.
  const float* w_w    = (const float*)d_in[4];
  const float* b_w    = (const float*)d_in[5];
  const float* w_proj = (const float*)d_in[6];
  const float* b_proj = (const float*)d_in[7];
  float* out = (float*)d_out;

  const int M = Bsz * Nseq;  // 4096
  char* ws = (char*)d_ws;
  _Float16* A16   = (_Float16*)ws;                   // 4096x768
  _Float16* BtQKV = A16   + (size_t)M * Cdim;        // 2304x768
  _Float16* BtPrj = BtQKV + (size_t)(3*Cdim) * Cdim; // 768x768
  _Float16* qkv16 = BtPrj + (size_t)Cdim * Cdim;     // 4096x2304
  _Float16* Vt    = qkv16 + (size_t)M * 3 * Cdim;    // (B*H*64)x1024
  _Float16* x16   = Vt    + (size_t)M * Cdim;        // 4096x768
  float*    dpart = (float*)(x16 + (size_t)M * Cdim);        // 49152x8
  float*    dinv  = dpart + (size_t)Bsz*Hn*Nseq*8;           // 49152
  float*    x32   = dinv  + (size_t)Bsz*Hn*Nseq;             // 4096x768

  cvt_f32_f16<<<dim3((M * Cdim) / 1024), 256, 0, stream>>>(inputs, A16);
  transpose_cvt<<<dim3((3*Cdim)/64, Cdim/64), 256, 0, stream>>>(w_qkv, BtQKV, Cdim, 3*Cdim);
  transpose_cvt<<<dim3(Cdim/64, Cdim/64), 256, 0, stream>>>(w_proj, BtPrj, Cdim, Cdim);

  gemm_f16<<<dim3((3*Cdim)/128, M/128), 256, 0, stream>>>(
      A16, BtQKV, nullptr, qkv16, nullptr, M, 3*Cdim, Cdim);

  prep_v<<<dim3(Bsz*Hn*16), 256, 0, stream>>>(qkv16, Vt);

  dsum_k<<<dim3(Bsz*64*8), 256, 0, stream>>>(qkv16, w_l, dpart);
  dinv_k<<<dim3(Bsz*Hn*Nseq/256), 256, 0, stream>>>(dpart, dinv);

  hipMemsetAsync(x32, 0, (size_t)M*Cdim*sizeof(float), stream);
  pvmix_k<<<dim3(Bsz*64*4), 256, 0, stream>>>(
      qkv16, Vt, dinv, w_l, w_w, b_w, x32);

  cvt_f32_f16<<<dim3((M * Cdim) / 1024), 256, 0, stream>>>(x32, x16);

  gemm_f16<<<dim3(Cdim/128, M/128), 256, 0, stream>>>(
      x16, BtPrj, b_proj, nullptr, out, M, Cdim, Cdim);
}

// Round 11
// 416.742 us; speedup vs baseline: 1.3265x; 1.0087x over previous
//
#include <hip/hip_runtime.h>

// TalkingHeadAttention: B=4, N=1024, C=768, H=12, HD=64
// Round 11: materialize P~ = exp(L-6) (fp16, 100 MB) to kill recompute and
// register pressure (r10 showed true reg use = arch 128 + acc ~48 -> 2
// waves/SIMD cap regardless of grid).
//  - qkexp_k: QK (head-PAIRS: only 8 acc live) + w_l mix + exp -> Pt. No
//    barriers, ~125 total regs -> 4 waves/SIMD. dsum_k deleted.
//  - dinv2_k: denominators by re-reading Pt (memory-bound).
//  - pvmix2_k: load Pt, scale dinv, w_w mix, PV. ~115 regs -> 4 waves/SIMD.
//  - Runtime fallback to the round-10 path (dsum_k/pvmix_k) if ws_size < 156MB.
// b_l dropped (cancels in softmax); b_w folded into mixed-prob init.

#define Bsz   4
#define Nseq  1024
#define Cdim  768
#define Hn    12
#define HDim  64

typedef __attribute__((ext_vector_type(4))) float    f32x4;
typedef __attribute__((ext_vector_type(8))) _Float16 f16x8;
typedef __attribute__((ext_vector_type(4))) _Float16 f16x4;

#define MFMA_F16(A, B, C) __builtin_amdgcn_mfma_f32_16x16x32_f16(A, B, C, 0, 0, 0)

// ---------------- fp32 -> fp16 cast ----------------------------------------
__global__ __launch_bounds__(256) void cvt_f32_f16(
    const float* __restrict__ in, _Float16* __restrict__ out)
{
  const size_t i = (size_t)(blockIdx.x * 256 + threadIdx.x) * 4;
  float4 v = *(const float4*)(in + i);
  f16x4 o;
  o[0] = (_Float16)v.x; o[1] = (_Float16)v.y;
  o[2] = (_Float16)v.z; o[3] = (_Float16)v.w;
  *(f16x4*)(out + i) = o;
}

// ------------- transpose + cast: in[R][C] fp32 -> out[C][R] fp16 -----------
__global__ __launch_bounds__(256) void transpose_cvt(
    const float* __restrict__ in, _Float16* __restrict__ out, int R, int C)
{
  __shared__ float T[64][65];
  const int c0 = blockIdx.x * 64, r0 = blockIdx.y * 64;
  const int lr = threadIdx.x >> 4, lc = (threadIdx.x & 15) * 4;
#pragma unroll
  for (int i = 0; i < 4; ++i) {
    float4 v = *(const float4*)(in + (size_t)(r0 + lr + i*16) * C + c0 + lc);
    T[lr+i*16][lc+0] = v.x; T[lr+i*16][lc+1] = v.y;
    T[lr+i*16][lc+2] = v.z; T[lr+i*16][lc+3] = v.w;
  }
  __syncthreads();
#pragma unroll
  for (int i = 0; i < 4; ++i) {
    const int orow = lr + i*16;
    f16x4 o;
#pragma unroll
    for (int j = 0; j < 4; ++j) o[j] = (_Float16)T[lc+j][orow];
    *(f16x4*)(out + (size_t)(c0 + orow) * R + r0 + lc) = o;
  }
}

// ---------------- fp16 MFMA GEMM, BT form ----------------------------------
__global__ __launch_bounds__(256, 2) void gemm_f16(
    const _Float16* __restrict__ A, const _Float16* __restrict__ Bt,
    const float* __restrict__ bias, _Float16* __restrict__ C16,
    float* __restrict__ C32, int M, int N, int K)
{
  __shared__ _Float16 sA[2][4][512];
  __shared__ _Float16 sB[2][4][512];
  const int tid = threadIdx.x;
  const int w = tid >> 6, lane = tid & 63;
  const int m0 = blockIdx.y * 128, n0 = blockIdx.x * 128;
  const int frow = lane & 15, fk8 = lane >> 4;

  f32x4 acc[4][4];
#pragma unroll
  for (int i = 0; i < 4; ++i)
#pragma unroll
    for (int j = 0; j < 4; ++j) acc[i][j] = (f32x4)0.f;

  const _Float16* gsrc = (w < 2)
      ? A  + (size_t)(m0 + w*64 + frow) * K + fk8 * 8
      : Bt + (size_t)(n0 + (w - 2)*64 + frow) * K + fk8 * 8;

  for (int kt = 0; kt < K; kt += 32) {
    f16x8 st[4];
#pragma unroll
    for (int j = 0; j < 4; ++j)
      st[j] = *(const f16x8*)(gsrc + kt + (size_t)j * 16 * K);
    __syncthreads();
    if (w < 2) {
#pragma unroll
      for (int j = 0; j < 4; ++j) *(f16x8*)&sA[w][j][lane*8] = st[j];
    } else {
#pragma unroll
      for (int j = 0; j < 4; ++j) *(f16x8*)&sB[w-2][j][lane*8] = st[j];
    }
    __syncthreads();
    f16x8 af[4], bf[4];
#pragma unroll
    for (int mi = 0; mi < 4; ++mi) af[mi] = *(const f16x8*)&sA[w & 1][mi][lane*8];
#pragma unroll
    for (int ni = 0; ni < 4; ++ni) bf[ni] = *(const f16x8*)&sB[w >> 1][ni][lane*8];
#pragma unroll
    for (int mi = 0; mi < 4; ++mi)
#pragma unroll
      for (int ni = 0; ni < 4; ++ni)
        acc[mi][ni] = MFMA_F16(af[mi], bf[ni], acc[mi][ni]);
  }

  const int m0w = m0 + (w & 1) * 64, n0w = n0 + (w >> 1) * 64;
#pragma unroll
  for (int mi = 0; mi < 4; ++mi)
#pragma unroll
    for (int ni = 0; ni < 4; ++ni) {
      const int n = n0w + ni*16 + (lane & 15);
#pragma unroll
      for (int r = 0; r < 4; ++r) {
        const int m = m0w + mi*16 + (lane >> 4)*4 + r;
        if (C16) C16[(size_t)m * N + n] = (_Float16)acc[mi][ni][r];
        else     C32[(size_t)m * N + n] = acc[mi][ni][r] + bias[n];
      }
    }
}

// ---------------- prep: V block of qkv16 -> per-head V^T fp16 --------------
__global__ __launch_bounds__(256) void prep_v(
    const _Float16* __restrict__ qkv16, _Float16* __restrict__ Vt)
{
  __shared__ float vt[64][65];
  const int id = blockIdx.x;
  const int nt = id & 15;
  const int h  = (id >> 4) % Hn;
  const int b  = id / (16 * Hn);
  const int n0 = nt * 64;
  const int tid = threadIdx.x;
  const int row = tid >> 2;
  const int c0  = (tid & 3) * 16;

  const _Float16* src = qkv16 + (size_t)(b*Nseq + n0 + row) * (3*Cdim) + 2*Cdim + h*HDim + c0;
  f16x8 v0 = *(const f16x8*)src;
  f16x8 v1 = *(const f16x8*)(src + 8);
#pragma unroll
  for (int j = 0; j < 8; ++j) {
    vt[c0+j][row]   = (float)v0[j];
    vt[c0+8+j][row] = (float)v1[j];
  }
  __syncthreads();
  f16x8 o0, o1;
#pragma unroll
  for (int j = 0; j < 8; ++j) {
    o0[j] = (_Float16)vt[row][c0+j];
    o1[j] = (_Float16)vt[row][c0+8+j];
  }
  _Float16* dst = Vt + (size_t)((b*Hn + h)*HDim + row) * Nseq + n0 + c0;
  *(f16x8*)dst = o0;
  *(f16x8*)(dst + 8) = o1;
}

// ============ NEW PATH: QK + mix + exp -> Pt (fp16) ========================
// grid = b(4) x qtile(64) x chunk(8) = 2048; 256 thr, 4 waves; wave w owns
// keys ch*128 + kg*64 + w*16 + col. Heads processed in PAIRS so only 8 acc
// VGPRs are live; L[4][12] accumulates in arch regs. Barrier-free main loop.
// Pt layout: [b][q][k][12] fp16.
__global__ __launch_bounds__(256) void qkexp_k(
    const _Float16* __restrict__ qkv16, const float* __restrict__ w_l,
    _Float16* __restrict__ Pt)
{
  __shared__ __attribute__((aligned(16))) float wl_s[144];
  const int tid = threadIdx.x;
  const int w = tid >> 6, lane = tid & 63;
  const int col = lane & 15, grp = lane >> 4;
  const int ch = blockIdx.x & 7;
  const int qt = (blockIdx.x >> 3) & 63;
  const int b  = blockIdx.x >> 9;
  const int q0 = qt << 4;

  if (tid < 144) wl_s[tid] = w_l[tid] * 0.125f;

  f16x8 qf[12][2];
  {
    const _Float16* qrow = qkv16 + (size_t)(b*Nseq + q0 + col) * (3*Cdim) + grp*8;
#pragma unroll
    for (int h = 0; h < 12; ++h) {
      qf[h][0] = *(const f16x8*)(qrow + h*HDim);
      qf[h][1] = *(const f16x8*)(qrow + h*HDim + 32);
    }
  }
  __syncthreads();

  for (int kg = 0; kg < 2; ++kg) {
    const int key = ch*128 + kg*64 + w*16 + col;
    const _Float16* krow = qkv16 + (size_t)(b*Nseq + key) * (3*Cdim) + Cdim + grp*8;
    float L[4][12];
#pragma unroll
    for (int r = 0; r < 4; ++r)
#pragma unroll
      for (int g = 0; g < 12; ++g) L[r][g] = 0.f;

#pragma unroll
    for (int hp = 0; hp < 6; ++hp) {
      const int h0 = hp * 2;
      f16x8 b00 = *(const f16x8*)(krow + h0*HDim);
      f16x8 b01 = *(const f16x8*)(krow + h0*HDim + 32);
      f16x8 b10 = *(const f16x8*)(krow + (h0+1)*HDim);
      f16x8 b11 = *(const f16x8*)(krow + (h0+1)*HDim + 32);
      f32x4 S0 = (f32x4)0.f, S1 = (f32x4)0.f;
      S0 = MFMA_F16(qf[h0][0],   b00, S0);
      S0 = MFMA_F16(qf[h0][1],   b01, S0);
      S1 = MFMA_F16(qf[h0+1][0], b10, S1);
      S1 = MFMA_F16(qf[h0+1][1], b11, S1);
      const f32x4 wa0 = *(const f32x4*)&wl_s[h0*12];
      const f32x4 wa1 = *(const f32x4*)&wl_s[h0*12+4];
      const f32x4 wa2 = *(const f32x4*)&wl_s[h0*12+8];
      const f32x4 wb0 = *(const f32x4*)&wl_s[(h0+1)*12];
      const f32x4 wb1 = *(const f32x4*)&wl_s[(h0+1)*12+4];
      const f32x4 wb2 = *(const f32x4*)&wl_s[(h0+1)*12+8];
#pragma unroll
      for (int r = 0; r < 4; ++r) {
        const float s0 = S0[r], s1 = S1[r];
#pragma unroll
        for (int j = 0; j < 4; ++j) {
          L[r][j]   = fmaf(s0, wa0[j], fmaf(s1, wb0[j], L[r][j]));
          L[r][4+j] = fmaf(s0, wa1[j], fmaf(s1, wb1[j], L[r][4+j]));
          L[r][8+j] = fmaf(s0, wa2[j], fmaf(s1, wb2[j], L[r][8+j]));
        }
      }
    }
#pragma unroll
    for (int r = 0; r < 4; ++r) {
      const int q = q0 + grp*4 + r;
      f16x8 o0; f16x4 o1;
#pragma unroll
      for (int g = 0; g < 8; ++g) o0[g] = (_Float16)__expf(L[r][g] - 6.0f);
#pragma unroll
      for (int g = 0; g < 4; ++g) o1[g] = (_Float16)__expf(L[r][8+g] - 6.0f);
      _Float16* dst = Pt + ((size_t)(b*Nseq + q)*Nseq + key) * 12;
      *(f16x8*)dst = o0;
      *(f16x4*)(dst + 8) = o1;
    }
  }
}

// ---- denominators by re-reading Pt (self-consistent with quantized P~) ----
// grid = B*N = 4096 blocks (one per (b,q)); 256 thr; thread sums 4 keys.
__global__ __launch_bounds__(256) void dinv2_k(
    const _Float16* __restrict__ Pt, float* __restrict__ dinv)
{
  __shared__ float red[4][12];
  const int tid = threadIdx.x;
  const int b = blockIdx.x >> 10, q = blockIdx.x & 1023;
  const int lane = tid & 63, w = tid >> 6;
  float acc[12];
#pragma unroll
  for (int g = 0; g < 12; ++g) acc[g] = 0.f;
#pragma unroll
  for (int j = 0; j < 4; ++j) {
    const int k = tid + j*256;
    const _Float16* p = Pt + ((size_t)(b*Nseq + q)*Nseq + k) * 12;
    f16x8 a = *(const f16x8*)p;
    f16x4 c = *(const f16x4*)(p + 8);
#pragma unroll
    for (int g = 0; g < 8; ++g) acc[g] += (float)a[g];
#pragma unroll
    for (int g = 0; g < 4; ++g) acc[8+g] += (float)c[g];
  }
#pragma unroll
  for (int g = 0; g < 12; ++g) {
    float v = acc[g];
    v += __shfl_xor(v, 1, 64);  v += __shfl_xor(v, 2, 64);
    v += __shfl_xor(v, 4, 64);  v += __shfl_xor(v, 8, 64);
    v += __shfl_xor(v, 16, 64); v += __shfl_xor(v, 32, 64);
    acc[g] = v;
  }
  if (lane == 0) {
#pragma unroll
    for (int g = 0; g < 12; ++g) red[w][g] = acc[g];
  }
  __syncthreads();
  if (tid < 12)
    dinv[(size_t)(b*Hn + tid)*Nseq + q] =
        1.0f / (red[0][tid] + red[1][tid] + red[2][tid] + red[3][tid]);
}

// ---- pass B from Pt: scale dinv, w_w mix (+b_w), PV ----------------------
// grid = b(4) x qtile(64) x keyquarter(4) = 1024 blocks; 256 thr, 4 waves.
__global__ __launch_bounds__(256) void pvmix2_k(
    const _Float16* __restrict__ Pt, const _Float16* __restrict__ Vt,
    const float* __restrict__ dinv, const float* __restrict__ w_w,
    const float* __restrict__ b_w, float* __restrict__ x32)
{
  __shared__ _Float16 P_s[12][16][72];
  __shared__ float dinv_s[16][12];
  __shared__ __attribute__((aligned(16))) float ww_s[144];
  __shared__ float bw_s[12];

  const int tid = threadIdx.x;
  const int w = tid >> 6, lane = tid & 63;
  const int col = lane & 15, grp = lane >> 4;
  const int kq = blockIdx.x & 3;
  const int qt = (blockIdx.x >> 2) & 63;
  const int b  = blockIdx.x >> 8;
  const int q0 = qt << 4;

  if (tid < 144) ww_s[tid] = w_w[tid];
  if (tid < 12)  bw_s[tid] = b_w[tid];
  if (tid < 192) {
    const int q = tid / 12, g = tid % 12;
    dinv_s[q][g] = dinv[(size_t)(b*Hn + g)*Nseq + q0 + q];
  }
  __syncthreads();

  f32x4 Y[12];
#pragma unroll
  for (int g2 = 0; g2 < 12; ++g2) Y[g2] = (f32x4)0.f;

  for (int c = kq*4; c < kq*4 + 4; ++c) {
    const int k0 = c * 64;
    // load this thread's 4 P~ points (global, before touching P_s)
    f16x8 p0[4]; f16x4 p1[4];
#pragma unroll
    for (int r = 0; r < 4; ++r) {
      const _Float16* p = Pt + ((size_t)(b*Nseq + q0 + grp*4 + r)*Nseq
                                + k0 + w*16 + col) * 12;
      p0[r] = *(const f16x8*)p;
      p1[r] = *(const f16x4*)(p + 8);
    }
    __syncthreads();   // previous chunk's PV reads of P_s complete
#pragma unroll
    for (int r = 0; r < 4; ++r) {
      const int q = grp*4 + r;
      float att2[12];
#pragma unroll
      for (int g2 = 0; g2 < 12; ++g2) att2[g2] = bw_s[g2];
#pragma unroll
      for (int g = 0; g < 12; ++g) {
        const float pv = (float)(g < 8 ? p0[r][g] : p1[r][g-8]);
        const float pr = pv * dinv_s[q][g];
        const f32x4 w0 = *(const f32x4*)&ww_s[g*12];
        const f32x4 w1 = *(const f32x4*)&ww_s[g*12+4];
        const f32x4 w2 = *(const f32x4*)&ww_s[g*12+8];
#pragma unroll
        for (int j = 0; j < 4; ++j) {
          att2[j]   = fmaf(pr, w0[j], att2[j]);
          att2[4+j] = fmaf(pr, w1[j], att2[4+j]);
          att2[8+j] = fmaf(pr, w2[j], att2[8+j]);
        }
      }
#pragma unroll
      for (int g2 = 0; g2 < 12; ++g2)
        P_s[g2][q][w*16 + col] = (_Float16)att2[g2];
    }
    __syncthreads();   // P_s complete
#pragma unroll
    for (int g2 = 0; g2 < 12; ++g2) {
      f16x8 a0 = *(const f16x8*)&P_s[g2][col][grp*8];
      f16x8 a1 = *(const f16x8*)&P_s[g2][col][32 + grp*8];
      const _Float16* vb = Vt + (size_t)((b*Hn + g2)*HDim + w*16 + col) * Nseq
                           + k0 + grp*8;
      f16x8 v0 = *(const f16x8*)vb;
      f16x8 v1 = *(const f16x8*)(vb + 32);
      Y[g2] = MFMA_F16(a0, v0, Y[g2]);
      Y[g2] = MFMA_F16(a1, v1, Y[g2]);
    }
  }

#pragma unroll
  for (int g2 = 0; g2 < 12; ++g2)
#pragma unroll
    for (int r = 0; r < 4; ++r)
      atomicAdd(&x32[(size_t)(b*Nseq + q0 + grp*4 + r) * Cdim + g2*HDim + w*16 + col],
                Y[g2][r]);
}

// ============ FALLBACK PATH (round-10, ws-light) ===========================
__global__ __launch_bounds__(256, 2) void dsum_k(
    const _Float16* __restrict__ qkv16, const float* __restrict__ w_l,
    float* __restrict__ dpart)
{
  __shared__ __attribute__((aligned(16))) float wl_s[144];
  __shared__ float dred[4][16][12];
  const int tid = threadIdx.x;
  const int w = tid >> 6, lane = tid & 63;
  const int col = lane & 15, grp = lane >> 4;
  const int ch = blockIdx.x & 7;
  const int qt = (blockIdx.x >> 3) & 63;
  const int b  = blockIdx.x >> 9;
  const int q0 = qt << 4;

  if (tid < 144) wl_s[tid] = w_l[tid] * 0.125f;

  f16x8 qf[12][2];
  {
    const _Float16* qrow = qkv16 + (size_t)(b*Nseq + q0 + col) * (3*Cdim) + grp*8;
#pragma unroll
    for (int h = 0; h < 12; ++h) {
      qf[h][0] = *(const f16x8*)(qrow + h*HDim);
      qf[h][1] = *(const f16x8*)(qrow + h*HDim + 32);
    }
  }
  __syncthreads();

  float dacc[4][12];
#pragma unroll
  for (int r = 0; r < 4; ++r)
#pragma unroll
    for (int g = 0; g < 12; ++g) dacc[r][g] = 0.f;

#pragma unroll
  for (int kg = 0; kg < 2; ++kg) {
    const int key = ch*128 + kg*64 + w*16 + col;
    const _Float16* krow = qkv16 + (size_t)(b*Nseq + key) * (3*Cdim) + Cdim + grp*8;
    f32x4 S[12];
#pragma unroll
    for (int h = 0; h < 12; ++h) {
      f16x8 b0 = *(const f16x8*)(krow + h*HDim);
      f16x8 b1 = *(const f16x8*)(krow + h*HDim + 32);
      f32x4 s = (f32x4)0.f;
      s = MFMA_F16(qf[h][0], b0, s);
      S[h] = MFMA_F16(qf[h][1], b1, s);
    }
#pragma unroll
    for (int r = 0; r < 4; ++r) {
      float L[12];
#pragma unroll
      for (int g = 0; g < 12; ++g) L[g] = 0.f;
#pragma unroll
      for (int h = 0; h < 12; ++h) {
        const float s = S[h][r];
        const f32x4 w0 = *(const f32x4*)&wl_s[h*12];
        const f32x4 w1 = *(const f32x4*)&wl_s[h*12+4];
        const f32x4 w2 = *(const f32x4*)&wl_s[h*12+8];
#pragma unroll
        for (int j = 0; j < 4; ++j) {
          L[j]   = fmaf(s, w0[j], L[j]);
          L[4+j] = fmaf(s, w1[j], L[4+j]);
          L[8+j] = fmaf(s, w2[j], L[8+j]);
        }
      }
#pragma unroll
      for (int g = 0; g < 12; ++g) dacc[r][g] += __expf(L[g] - 6.0f);
    }
  }
#pragma unroll
  for (int r = 0; r < 4; ++r)
#pragma unroll
    for (int g = 0; g < 12; ++g) {
      float v = dacc[r][g];
      v += __shfl_xor(v, 1, 64);
      v += __shfl_xor(v, 2, 64);
      v += __shfl_xor(v, 4, 64);
      v += __shfl_xor(v, 8, 64);
      dacc[r][g] = v;
    }
  if (col == 0) {
#pragma unroll
    for (int r = 0; r < 4; ++r)
#pragma unroll
      for (int g = 0; g < 12; ++g) dred[w][grp*4+r][g] = dacc[r][g];
  }
  __syncthreads();
  if (tid < 192) {
    const int q = tid / 12, g = tid % 12;
    const float s = dred[0][q][g] + dred[1][q][g] + dred[2][q][g] + dred[3][q][g];
    dpart[((size_t)((b*Hn + g)*Nseq) + q0 + q) * 8 + ch] = s;
  }
}

__global__ __launch_bounds__(256) void dinv_k(
    const float* __restrict__ dpart, float* __restrict__ dinv)
{
  const int i = blockIdx.x * 256 + threadIdx.x;
  const float* p = dpart + (size_t)i * 8;
  f32x4 a = *(const f32x4*)p;
  f32x4 c = *(const f32x4*)(p + 4);
  dinv[i] = 1.0f / (a[0]+a[1]+a[2]+a[3]+c[0]+c[1]+c[2]+c[3]);
}

__global__ __launch_bounds__(256, 2) void pvmix_k(
    const _Float16* __restrict__ qkv16, const _Float16* __restrict__ Vt,
    const float* __restrict__ dinv,
    const float* __restrict__ w_l, const float* __restrict__ w_w,
    const float* __restrict__ b_w, float* __restrict__ x32)
{
  __shared__ _Float16 P_s[12][16][72];
  __shared__ float dinv_s[16][12];
  __shared__ __attribute__((aligned(16))) float wl_s[144];
  __shared__ __attribute__((aligned(16))) float ww_s[144];
  __shared__ float bw_s[12];

  const int tid = threadIdx.x;
  const int w = tid >> 6, lane = tid & 63;
  const int col = lane & 15, grp = lane >> 4;
  const int kh = blockIdx.x & 1;
  const int qt = (blockIdx.x >> 1) & 63;
  const int b  = blockIdx.x >> 7;
  const int q0 = qt << 4;

  if (tid < 144) { wl_s[tid] = w_l[tid] * 0.125f; ww_s[tid] = w_w[tid]; }
  if (tid < 12)  bw_s[tid] = b_w[tid];
  if (tid < 192) {
    const int q = tid / 12, g = tid % 12;
    dinv_s[q][g] = dinv[(size_t)((b*Hn + g)*Nseq) + q0 + q];
  }

  f16x8 qf[12][2];
  {
    const _Float16* qrow = qkv16 + (size_t)(b*Nseq + q0 + col) * (3*Cdim) + grp*8;
#pragma unroll
    for (int h = 0; h < 12; ++h) {
      qf[h][0] = *(const f16x8*)(qrow + h*HDim);
      qf[h][1] = *(const f16x8*)(qrow + h*HDim + 32);
    }
  }
  __syncthreads();

  f32x4 Y[12];
#pragma unroll
  for (int g2 = 0; g2 < 12; ++g2) Y[g2] = (f32x4)0.f;

  for (int c = kh*8; c < kh*8 + 8; ++c) {
    const int k0 = c * 64;
    const _Float16* krow = qkv16 + (size_t)(b*Nseq + k0 + w*16 + col) * (3*Cdim)
                           + Cdim + grp*8;
    f32x4 S[12];
#pragma unroll
    for (int h = 0; h < 12; ++h) {
      f16x8 b0 = *(const f16x8*)(krow + h*HDim);
      f16x8 b1 = *(const f16x8*)(krow + h*HDim + 32);
      f32x4 s = (f32x4)0.f;
      s = MFMA_F16(qf[h][0], b0, s);
      S[h] = MFMA_F16(qf[h][1], b1, s);
    }
    __syncthreads();
#pragma unroll
    for (int r = 0; r < 4; ++r) {
      const int q = grp*4 + r;
      float L[12];
#pragma unroll
      for (int g = 0; g < 12; ++g) L[g] = 0.f;
#pragma unroll
      for (int h = 0; h < 12; ++h) {
        const float s = S[h][r];
        const f32x4 w0 = *(const f32x4*)&wl_s[h*12];
        const f32x4 w1 = *(const f32x4*)&wl_s[h*12+4];
        const f32x4 w2 = *(const f32x4*)&wl_s[h*12+8];
#pragma unroll
        for (int j = 0; j < 4; ++j) {
          L[j]   = fmaf(s, w0[j], L[j]);
          L[4+j] = fmaf(s, w1[j], L[4+j]);
          L[8+j] = fmaf(s, w2[j], L[8+j]);
        }
      }
      float att2[12];
#pragma unroll
      for (int g2 = 0; g2 < 12; ++g2) att2[g2] = bw_s[g2];
#pragma unroll
      for (int g = 0; g < 12; ++g) {
        const float pr = __expf(L[g] - 6.0f) * dinv_s[q][g];
        const f32x4 w0 = *(const f32x4*)&ww_s[g*12];
        const f32x4 w1 = *(const f32x4*)&ww_s[g*12+4];
        const f32x4 w2 = *(const f32x4*)&ww_s[g*12+8];
#pragma unroll
        for (int j = 0; j < 4; ++j) {
          att2[j]   = fmaf(pr, w0[j], att2[j]);
          att2[4+j] = fmaf(pr, w1[j], att2[4+j]);
          att2[8+j] = fmaf(pr, w2[j], att2[8+j]);
        }
      }
#pragma unroll
      for (int g2 = 0; g2 < 12; ++g2)
        P_s[g2][q][w*16 + col] = (_Float16)att2[g2];
    }
    __syncthreads();
#pragma unroll
    for (int g2 = 0; g2 < 12; ++g2) {
      f16x8 a0 = *(const f16x8*)&P_s[g2][col][grp*8];
      f16x8 a1 = *(const f16x8*)&P_s[g2][col][32 + grp*8];
      const _Float16* vb = Vt + (size_t)((b*Hn + g2)*HDim + w*16 + col) * Nseq
                           + k0 + grp*8;
      f16x8 v0 = *(const f16x8*)vb;
      f16x8 v1 = *(const f16x8*)(vb + 32);
      Y[g2] = MFMA_F16(a0, v0, Y[g2]);
      Y[g2] = MFMA_F16(a1, v1, Y[g2]);
    }
  }

#pragma unroll
  for (int g2 = 0; g2 < 12; ++g2)
#pragma unroll
    for (int r = 0; r < 4; ++r)
      atomicAdd(&x32[(size_t)(b*Nseq + q0 + grp*4 + r) * Cdim + g2*HDim + w*16 + col],
                Y[g2][r]);
}

extern "C" void kernel_launch(void* const* d_in, const int* in_sizes, int n_in,
                              void* d_out, int out_size, void* d_ws, size_t ws_size,
                              hipStream_t stream) {
  (void)in_sizes; (void)n_in; (void)out_size;
  const float* inputs = (const float*)d_in[0];
  const float* w_qkv  = (const float*)d_in[1];
  const float* w_l    = (const float*)d_in[2];
  // d_in[3] = b_l: cancels in softmax — unused.
  const float* w_w    = (const float*)d_in[4];
  const float* b_w    = (const float*)d_in[5];
  const float* w_proj = (const float*)d_in[6];
  const float* b_proj = (const float*)d_in[7];
  float* out = (float*)d_out;

  const int M = Bsz * Nseq;  // 4096
  char* ws = (char*)d_ws;
  _Float16* A16   = (_Float16*)ws;                   // 4096x768
  _Float16* BtQKV = A16   + (size_t)M * Cdim;        // 2304x768
  _Float16* BtPrj = BtQKV + (size_t)(3*Cdim) * Cdim; // 768x768
  _Float16* qkv16 = BtPrj + (size_t)Cdim * Cdim;     // 4096x2304
  _Float16* Vt    = qkv16 + (size_t)M * 3 * Cdim;    // (B*H*64)x1024
  _Float16* x16   = Vt    + (size_t)M * Cdim;        // 4096x768
  float*    dinv  = (float*)(x16 + (size_t)M * Cdim);        // 49152
  float*    x32   = dinv + (size_t)Bsz*Hn*Nseq;              // 4096x768 fp32
  char*     tail  = (char*)(x32 + (size_t)M * Cdim);
  _Float16* Pt    = (_Float16*)tail;                         // [b][q][k][12]
  float*    dpart = (float*)tail;                            // fallback only

  const size_t NEED = (size_t)(tail - ws) + (size_t)Bsz*Nseq*Nseq*12*sizeof(_Float16);

  cvt_f32_f16<<<dim3((M * Cdim) / 1024), 256, 0, stream>>>(inputs, A16);
  transpose_cvt<<<dim3((3*Cdim)/64, Cdim/64), 256, 0, stream>>>(w_qkv, BtQKV, Cdim, 3*Cdim);
  transpose_cvt<<<dim3(Cdim/64, Cdim/64), 256, 0, stream>>>(w_proj, BtPrj, Cdim, Cdim);

  gemm_f16<<<dim3((3*Cdim)/128, M/128), 256, 0, stream>>>(
      A16, BtQKV, nullptr, qkv16, nullptr, M, 3*Cdim, Cdim);

  prep_v<<<dim3(Bsz*Hn*16), 256, 0, stream>>>(qkv16, Vt);

  hipMemsetAsync(x32, 0, (size_t)M*Cdim*sizeof(float), stream);

  if (ws_size >= NEED) {
    // -------- new path: materialized P~ --------
    qkexp_k<<<dim3(Bsz*64*8), 256, 0, stream>>>(qkv16, w_l, Pt);
    dinv2_k<<<dim3(Bsz*Nseq), 256, 0, stream>>>(Pt, dinv);
    pvmix2_k<<<dim3(Bsz*64*4), 256, 0, stream>>>(
        Pt, Vt, dinv, w_w, b_w, x32);
  } else {
    // -------- fallback: round-10 recompute path --------
    dsum_k<<<dim3(Bsz*64*8), 256, 0, stream>>>(qkv16, w_l, dpart);
    dinv_k<<<dim3(Bsz*Hn*Nseq/256), 256, 0, stream>>>(dpart, dinv);
    pvmix_k<<<dim3(Bsz*64*2), 256, 0, stream>>>(
        qkv16, Vt, dinv, w_l, w_w, b_w, x32);
  }

  cvt_f32_f16<<<dim3((M * Cdim) / 1024), 256, 0, stream>>>(x32, x16);

  gemm_f16<<<dim3(Cdim/128, M/128), 256, 0, stream>>>(
      x16, BtPrj, b_proj, nullptr, out, M, Cdim, Cdim);
}